// Round 11
// baseline (47.289 us; speedup 1.0000x reference)
//
#include <hip/hip_runtime.h>

#define DIM 120
#define NB 16            // batch rows per block
#define NBP 20           // padded LDS stride in dwords (b128-aligned)
#define BLOCK 256        // one thread per output row
#define NG (NB / 4)      // float4 groups along b
#define NXCD 8

__device__ __forceinline__ int lower_bound(const int* __restrict__ a, int n, int v) {
    int lo = 0, hi = n;
    while (lo < hi) {
        int m = (lo + hi) >> 1;
        if (a[m] < v) lo = m + 1; else hi = m;
    }
    return lo;
}

// Single fused kernel: per-thread CSR bounds via binary search on the sorted
// out_indices (no preprocess kernel, no workspace), R8 hot loop and stores.
__global__ __launch_bounds__(BLOCK, 8) void tp_kernel(
    const float* __restrict__ in1, const float* __restrict__ in2,
    const float* __restrict__ pal,
    const int* __restrict__ i1, const int* __restrict__ i2,
    const int* __restrict__ oi, const int* __restrict__ cb,
    float* __restrict__ out, int H, int K, int nbx) {
    // bijective XCD-chunked swizzle over the o-block dimension
    int x = blockIdx.x;
    {
        const int q = nbx / NXCD, r = nbx % NXCD;
        const int xcd = x % NXCD, pos = x / NXCD;
        x = (xcd < r) ? (xcd * (q + 1) + pos) : (r * (q + 1) + (xcd - r) * q + pos);
    }

    __shared__ __align__(16) float s1t[DIM * NBP];
    __shared__ __align__(16) float s2t[DIM * NBP];

    // --- per-thread CSR bounds (searches overlap staging across waves) ---
    const int o = x * BLOCK + (int)threadIdx.x;
    const int om  = (o < H) ? o : H;
    const int om1 = (o + 1 < H) ? o + 1 : H;
    const int k0 = lower_bound(oi, K, om);
    const int k1 = lower_bound(oi, K, om1);

    // --- stage NB batch-rows transposed to [d][b] ---
    const int b0 = blockIdx.y * NB;
    for (int t = threadIdx.x; t < 2 * DIM * NG; t += BLOCK) {
        const int arr = (t >= DIM * NG);
        const int c = arr ? t - DIM * NG : t;
        const int d = c % DIM;
        const int g = c / DIM;
        const float* __restrict__ src = arr ? in2 : in1;
        const size_t base = (size_t)(b0 + 4 * g) * DIM + d;
        float4 v;
        v.x = src[base + 0 * DIM];
        v.y = src[base + 1 * DIM];
        v.z = src[base + 2 * DIM];
        v.w = src[base + 3 * DIM];
        float* dst = arr ? s2t : s1t;
        *(float4*)(dst + d * NBP + 4 * g) = v;
    }
    __syncthreads();

    if (o >= H) return;

    float acc[NB];
#pragma unroll
    for (int b = 0; b < NB; ++b) acc[b] = 0.0f;

    for (int k = k0; k < k1; ++k) {
        const int a = i1[k];
        const int c = i2[k];
        const float v = pal[cb[k]];
        const float4* __restrict__ pa = (const float4*)(s1t + a * NBP);
        const float4* __restrict__ pc = (const float4*)(s2t + c * NBP);
#pragma unroll
        for (int j = 0; j < NG; ++j) {
            const float4 x4 = pa[j];
            const float4 y4 = pc[j];
            acc[4 * j + 0] = fmaf(v * x4.x, y4.x, acc[4 * j + 0]);
            acc[4 * j + 1] = fmaf(v * x4.y, y4.y, acc[4 * j + 1]);
            acc[4 * j + 2] = fmaf(v * x4.z, y4.z, acc[4 * j + 2]);
            acc[4 * j + 3] = fmaf(v * x4.w, y4.w, acc[4 * j + 3]);
        }
    }

#pragma unroll
    for (int b = 0; b < NB; ++b)
        out[(size_t)(b0 + b) * H + o] = acc[b];
}

extern "C" void kernel_launch(void* const* d_in, const int* in_sizes, int n_in,
                              void* d_out, int out_size, void* d_ws, size_t ws_size,
                              hipStream_t stream) {
    const float* in1 = (const float*)d_in[0];
    const float* in2 = (const float*)d_in[1];
    const float* pal = (const float*)d_in[2];
    const int*   i1  = (const int*)d_in[3];
    const int*   i2  = (const int*)d_in[4];
    const int*   oi  = (const int*)d_in[5];
    const int*   cb  = (const int*)d_in[6];

    const int K = in_sizes[3];
    const int B = in_sizes[0] / DIM;   // 2048
    const int H = out_size / B;        // 14400

    const int nbx = (H + BLOCK - 1) / BLOCK;   // 57
    dim3 grid(nbx, B / NB);
    tp_kernel<<<grid, BLOCK, 0, stream>>>(in1, in2, pal, i1, i2, oi, cb,
                                          (float*)d_out, H, K, nbx);
}

// Round 12
// 33.380 us; speedup vs baseline: 1.4167x; 1.4167x over previous
//
#include <hip/hip_runtime.h>

#define DIM 120
#define NB 16            // batch rows per block
#define NBP 20           // padded LDS stride in dwords (b128-aligned)
#define BLOCK 1024       // one thread per output row; 4KB contiguous span per (block,b)
#define NG (NB / 4)      // float4 groups along b
#define NXCD 8

// ---- Fused preprocess: CSR row pointers + packed {i1,i2,palette} entries ----
__global__ void pre_kernel(const int* __restrict__ out_idx, int K, int H,
                           int* __restrict__ row_start,
                           const int* __restrict__ i1, const int* __restrict__ i2,
                           const int* __restrict__ cb, const float* __restrict__ pal,
                           uint2* __restrict__ ent) {
    int t = blockIdx.x * blockDim.x + threadIdx.x;
    if (t <= H) {
        int lo = 0, hi = K;
        while (lo < hi) {
            int mid = (lo + hi) >> 1;
            if (out_idx[mid] < t) lo = mid + 1; else hi = mid;
        }
        row_start[t] = lo;
    }
    if (t < K) {
        uint2 e;
        e.x = (unsigned)i1[t] | ((unsigned)i2[t] << 16);
        e.y = __float_as_uint(pal[cb[t]]);
        ent[t] = e;
    }
}

// ---- Main: R8 structure, BLOCK=1024 -> 4KB contiguous store spans ----
__global__ __launch_bounds__(BLOCK, 8) void tp_kernel(
    const float* __restrict__ in1, const float* __restrict__ in2,
    const uint2* __restrict__ ent, const int* __restrict__ row_start,
    float* __restrict__ out, int H, int nbx) {
    // bijective XCD-chunked swizzle over the o-block dimension
    int x = blockIdx.x;
    {
        const int q = nbx / NXCD, r = nbx % NXCD;
        const int xcd = x % NXCD, pos = x / NXCD;
        x = (xcd < r) ? (xcd * (q + 1) + pos) : (r * (q + 1) + (xcd - r) * q + pos);
    }

    __shared__ __align__(16) float s1t[DIM * NBP];
    __shared__ __align__(16) float s2t[DIM * NBP];

    // --- stage NB batch-rows transposed to [d][b] ---
    const int b0 = blockIdx.y * NB;
    for (int t = threadIdx.x; t < 2 * DIM * NG; t += BLOCK) {
        const int arr = (t >= DIM * NG);
        const int c = arr ? t - DIM * NG : t;
        const int d = c % DIM;
        const int g = c / DIM;
        const float* __restrict__ src = arr ? in2 : in1;
        const size_t base = (size_t)(b0 + 4 * g) * DIM + d;
        float4 v;
        v.x = src[base + 0 * DIM];
        v.y = src[base + 1 * DIM];
        v.z = src[base + 2 * DIM];
        v.w = src[base + 3 * DIM];
        float* dst = arr ? s2t : s1t;
        *(float4*)(dst + d * NBP + 4 * g) = v;
    }
    __syncthreads();

    const int o = x * BLOCK + (int)threadIdx.x;
    if (o >= H) return;
    const int k0 = row_start[o];
    const int k1 = row_start[o + 1];

    float acc[NB];
#pragma unroll
    for (int b = 0; b < NB; ++b) acc[b] = 0.0f;

    for (int k = k0; k < k1; ++k) {
        const uint2 e = ent[k];
        const float4* __restrict__ pa = (const float4*)(s1t + (e.x & 0xffffu) * NBP);
        const float4* __restrict__ pc = (const float4*)(s2t + (e.x >> 16) * NBP);
        const float v = __uint_as_float(e.y);
#pragma unroll
        for (int j = 0; j < NG; ++j) {
            const float4 x4 = pa[j];
            const float4 y4 = pc[j];
            acc[4 * j + 0] = fmaf(v * x4.x, y4.x, acc[4 * j + 0]);
            acc[4 * j + 1] = fmaf(v * x4.y, y4.y, acc[4 * j + 1]);
            acc[4 * j + 2] = fmaf(v * x4.z, y4.z, acc[4 * j + 2]);
            acc[4 * j + 3] = fmaf(v * x4.w, y4.w, acc[4 * j + 3]);
        }
    }

#pragma unroll
    for (int b = 0; b < NB; ++b)
        out[(size_t)(b0 + b) * H + o] = acc[b];
}

extern "C" void kernel_launch(void* const* d_in, const int* in_sizes, int n_in,
                              void* d_out, int out_size, void* d_ws, size_t ws_size,
                              hipStream_t stream) {
    const float* in1 = (const float*)d_in[0];
    const float* in2 = (const float*)d_in[1];
    const float* pal = (const float*)d_in[2];
    const int*   i1  = (const int*)d_in[3];
    const int*   i2  = (const int*)d_in[4];
    const int*   oi  = (const int*)d_in[5];
    const int*   cb  = (const int*)d_in[6];

    const int K = in_sizes[3];
    const int B = in_sizes[0] / DIM;   // 2048
    const int H = out_size / B;        // 14400

    uint2* ent = (uint2*)d_ws;
    int* row_start = (int*)((char*)d_ws + (size_t)K * sizeof(uint2));

    {
        const int n = (K > H + 1) ? K : (H + 1);
        pre_kernel<<<(n + 255) / 256, 256, 0, stream>>>(oi, K, H, row_start,
                                                        i1, i2, cb, pal, ent);
    }

    const int nbx = (H + BLOCK - 1) / BLOCK;   // 15
    dim3 grid(nbx, B / NB);
    tp_kernel<<<grid, BLOCK, 0, stream>>>(in1, in2, ent, row_start,
                                          (float*)d_out, H, nbx);
}

// Round 13
// 31.690 us; speedup vs baseline: 1.4922x; 1.0533x over previous
//
#include <hip/hip_runtime.h>

#define DIM 120
#define NB 16            // batch rows per block
#define NBP 20           // padded LDS stride in dwords (b128-aligned)
#define BLOCK 256        // one thread per output row
#define NG (NB / 4)      // float4 groups along b
#define NXCD 8

// ---- Fused preprocess: CSR row pointers + packed {i1,i2,palette} entries ----
__global__ void pre_kernel(const int* __restrict__ out_idx, int K, int H,
                           int* __restrict__ row_start,
                           const int* __restrict__ i1, const int* __restrict__ i2,
                           const int* __restrict__ cb, const float* __restrict__ pal,
                           uint2* __restrict__ ent) {
    int t = blockIdx.x * blockDim.x + threadIdx.x;
    if (t <= H) {
        int lo = 0, hi = K;
        while (lo < hi) {
            int mid = (lo + hi) >> 1;
            if (out_idx[mid] < t) lo = mid + 1; else hi = mid;
        }
        row_start[t] = lo;
    }
    if (t < K) {
        uint2 e;
        e.x = (unsigned)i1[t] | ((unsigned)i2[t] << 16);
        e.y = __float_as_uint(pal[cb[t]]);
        ent[t] = e;
    }
}

// ---- Main: R8 structure + NONTEMPORAL output stores (bypass L2 dirty churn) ----
__global__ __launch_bounds__(BLOCK, 8) void tp_kernel(
    const float* __restrict__ in1, const float* __restrict__ in2,
    const uint2* __restrict__ ent, const int* __restrict__ row_start,
    float* __restrict__ out, int H, int nbx) {
    // bijective XCD-chunked swizzle over the o-block dimension
    int x = blockIdx.x;
    {
        const int q = nbx / NXCD, r = nbx % NXCD;
        const int xcd = x % NXCD, pos = x / NXCD;
        x = (xcd < r) ? (xcd * (q + 1) + pos) : (r * (q + 1) + (xcd - r) * q + pos);
    }

    __shared__ __align__(16) float s1t[DIM * NBP];
    __shared__ __align__(16) float s2t[DIM * NBP];

    // --- stage NB batch-rows transposed to [d][b] ---
    const int b0 = blockIdx.y * NB;
    for (int t = threadIdx.x; t < 2 * DIM * NG; t += BLOCK) {
        const int arr = (t >= DIM * NG);
        const int c = arr ? t - DIM * NG : t;
        const int d = c % DIM;
        const int g = c / DIM;
        const float* __restrict__ src = arr ? in2 : in1;
        const size_t base = (size_t)(b0 + 4 * g) * DIM + d;
        float4 v;
        v.x = src[base + 0 * DIM];
        v.y = src[base + 1 * DIM];
        v.z = src[base + 2 * DIM];
        v.w = src[base + 3 * DIM];
        float* dst = arr ? s2t : s1t;
        *(float4*)(dst + d * NBP + 4 * g) = v;
    }
    __syncthreads();

    const int o = x * BLOCK + threadIdx.x;
    if (o >= H) return;
    const int k0 = row_start[o];
    const int k1 = row_start[o + 1];

    float acc[NB];
#pragma unroll
    for (int b = 0; b < NB; ++b) acc[b] = 0.0f;

    for (int k = k0; k < k1; ++k) {
        const uint2 e = ent[k];
        const float4* __restrict__ pa = (const float4*)(s1t + (e.x & 0xffffu) * NBP);
        const float4* __restrict__ pc = (const float4*)(s2t + (e.x >> 16) * NBP);
        const float v = __uint_as_float(e.y);
#pragma unroll
        for (int j = 0; j < NG; ++j) {
            const float4 x4 = pa[j];
            const float4 y4 = pc[j];
            acc[4 * j + 0] = fmaf(v * x4.x, y4.x, acc[4 * j + 0]);
            acc[4 * j + 1] = fmaf(v * x4.y, y4.y, acc[4 * j + 1]);
            acc[4 * j + 2] = fmaf(v * x4.z, y4.z, acc[4 * j + 2]);
            acc[4 * j + 3] = fmaf(v * x4.w, y4.w, acc[4 * j + 3]);
        }
    }

#pragma unroll
    for (int b = 0; b < NB; ++b)
        __builtin_nontemporal_store(acc[b], &out[(size_t)(b0 + b) * H + o]);
}

extern "C" void kernel_launch(void* const* d_in, const int* in_sizes, int n_in,
                              void* d_out, int out_size, void* d_ws, size_t ws_size,
                              hipStream_t stream) {
    const float* in1 = (const float*)d_in[0];
    const float* in2 = (const float*)d_in[1];
    const float* pal = (const float*)d_in[2];
    const int*   i1  = (const int*)d_in[3];
    const int*   i2  = (const int*)d_in[4];
    const int*   oi  = (const int*)d_in[5];
    const int*   cb  = (const int*)d_in[6];

    const int K = in_sizes[3];
    const int B = in_sizes[0] / DIM;   // 2048
    const int H = out_size / B;        // 14400

    uint2* ent = (uint2*)d_ws;
    int* row_start = (int*)((char*)d_ws + (size_t)K * sizeof(uint2));

    {
        const int n = (K > H + 1) ? K : (H + 1);
        pre_kernel<<<(n + 255) / 256, 256, 0, stream>>>(oi, K, H, row_start,
                                                        i1, i2, cb, pal, ent);
    }

    const int nbx = (H + BLOCK - 1) / BLOCK;   // 57
    dim3 grid(nbx, B / NB);
    tp_kernel<<<grid, BLOCK, 0, stream>>>(in1, in2, ent, row_start,
                                          (float*)d_out, H, nbx);
}

// Round 15
// 30.985 us; speedup vs baseline: 1.5262x; 1.0227x over previous
//
#include <hip/hip_runtime.h>

#define DIM 120
#define NB 16            // batch rows per block
#define NBP 20           // padded LDS stride in dwords (b128-aligned)
#define BLOCK 256        // one thread per output row
#define NG (NB / 4)      // float4 groups along b
#define NXCD 8
#define SMEM_FLOATS (2 * DIM * NBP)   // 4800 floats = 19.2 KB (>= 16 KB outbuf)

typedef float f32x4 __attribute__((ext_vector_type(4)));   // nt-store-legal vec4

// ---- Fused preprocess: CSR row pointers + packed {i1,i2,palette} entries ----
__global__ void pre_kernel(const int* __restrict__ out_idx, int K, int H,
                           int* __restrict__ row_start,
                           const int* __restrict__ i1, const int* __restrict__ i2,
                           const int* __restrict__ cb, const float* __restrict__ pal,
                           uint2* __restrict__ ent) {
    int t = blockIdx.x * blockDim.x + threadIdx.x;
    if (t <= H) {
        int lo = 0, hi = K;
        while (lo < hi) {
            int mid = (lo + hi) >> 1;
            if (out_idx[mid] < t) lo = mid + 1; else hi = mid;
        }
        row_start[t] = lo;
    }
    if (t < K) {
        uint2 e;
        e.x = (unsigned)i1[t] | ((unsigned)i2[t] << 16);
        e.y = __float_as_uint(pal[cb[t]]);
        ent[t] = e;
    }
}

// ---- Main: R13 (nt stores) + LDS output exchange -> 1KB contiguous nt bursts ----
__global__ __launch_bounds__(BLOCK, 8) void tp_kernel(
    const float* __restrict__ in1, const float* __restrict__ in2,
    const uint2* __restrict__ ent, const int* __restrict__ row_start,
    float* __restrict__ out, int H, int nbx) {
    // bijective XCD-chunked swizzle over the o-block dimension
    int x = blockIdx.x;
    {
        const int q = nbx / NXCD, r = nbx % NXCD;
        const int xcd = x % NXCD, pos = x / NXCD;
        x = (xcd < r) ? (xcd * (q + 1) + pos) : (r * (q + 1) + (xcd - r) * q + pos);
    }

    __shared__ __align__(16) float smem[SMEM_FLOATS];
    float* __restrict__ s1t = smem;
    float* __restrict__ s2t = smem + DIM * NBP;

    // --- stage NB batch-rows transposed to [d][b] ---
    const int b0 = blockIdx.y * NB;
    for (int t = threadIdx.x; t < 2 * DIM * NG; t += BLOCK) {
        const int arr = (t >= DIM * NG);
        const int c = arr ? t - DIM * NG : t;
        const int d = c % DIM;
        const int g = c / DIM;
        const float* __restrict__ src = arr ? in2 : in1;
        const size_t base = (size_t)(b0 + 4 * g) * DIM + d;
        float4 v;
        v.x = src[base + 0 * DIM];
        v.y = src[base + 1 * DIM];
        v.z = src[base + 2 * DIM];
        v.w = src[base + 3 * DIM];
        float* dst = arr ? s2t : s1t;
        *(float4*)(dst + d * NBP + 4 * g) = v;
    }
    __syncthreads();

    const int o0 = x * BLOCK;
    const int o = o0 + (int)threadIdx.x;
    const bool act = (o < H);

    float acc[NB];
#pragma unroll
    for (int b = 0; b < NB; ++b) acc[b] = 0.0f;

    if (act) {
        const int k0 = row_start[o];
        const int k1 = row_start[o + 1];
        for (int k = k0; k < k1; ++k) {
            const uint2 e = ent[k];
            const float4* __restrict__ pa = (const float4*)(s1t + (e.x & 0xffffu) * NBP);
            const float4* __restrict__ pc = (const float4*)(s2t + (e.x >> 16) * NBP);
            const float v = __uint_as_float(e.y);
#pragma unroll
            for (int j = 0; j < NG; ++j) {
                const float4 x4 = pa[j];
                const float4 y4 = pc[j];
                acc[4 * j + 0] = fmaf(v * x4.x, y4.x, acc[4 * j + 0]);
                acc[4 * j + 1] = fmaf(v * x4.y, y4.y, acc[4 * j + 1]);
                acc[4 * j + 2] = fmaf(v * x4.z, y4.z, acc[4 * j + 2]);
                acc[4 * j + 3] = fmaf(v * x4.w, y4.w, acc[4 * j + 3]);
            }
        }
    }
    __syncthreads();   // staging reads complete before overwriting smem

    if (o0 + BLOCK <= H) {
        // exchange: outbuf[b][t] overlaid on smem (16 KB), stride-1 conflict-free
#pragma unroll
        for (int b = 0; b < NB; ++b)
            smem[b * BLOCK + threadIdx.x] = acc[b];
        __syncthreads();
        // wave w, iter it -> b = 4*it + w; one 1KB contiguous NT dwordx4 burst
        const int wave = threadIdx.x >> 6;
        const int lane = threadIdx.x & 63;
#pragma unroll
        for (int it = 0; it < NB / 4; ++it) {
            const int b = it * 4 + wave;
            const f32x4 v = *(const f32x4*)(smem + b * BLOCK + 4 * lane);
            __builtin_nontemporal_store(
                v, (f32x4*)(out + (size_t)(b0 + b) * H + o0 + 4 * lane));
        }
    } else if (act) {
        // partial last tile: per-thread scalar nt stores
#pragma unroll
        for (int b = 0; b < NB; ++b)
            __builtin_nontemporal_store(acc[b], &out[(size_t)(b0 + b) * H + o]);
    }
}

extern "C" void kernel_launch(void* const* d_in, const int* in_sizes, int n_in,
                              void* d_out, int out_size, void* d_ws, size_t ws_size,
                              hipStream_t stream) {
    const float* in1 = (const float*)d_in[0];
    const float* in2 = (const float*)d_in[1];
    const float* pal = (const float*)d_in[2];
    const int*   i1  = (const int*)d_in[3];
    const int*   i2  = (const int*)d_in[4];
    const int*   oi  = (const int*)d_in[5];
    const int*   cb  = (const int*)d_in[6];

    const int K = in_sizes[3];
    const int B = in_sizes[0] / DIM;   // 2048
    const int H = out_size / B;        // 14400

    uint2* ent = (uint2*)d_ws;
    int* row_start = (int*)((char*)d_ws + (size_t)K * sizeof(uint2));

    {
        const int n = (K > H + 1) ? K : (H + 1);
        pre_kernel<<<(n + 255) / 256, 256, 0, stream>>>(oi, K, H, row_start,
                                                        i1, i2, cb, pal, ent);
    }

    const int nbx = (H + BLOCK - 1) / BLOCK;   // 57
    dim3 grid(nbx, B / NB);
    tp_kernel<<<grid, BLOCK, 0, stream>>>(in1, in2, ent, row_start,
                                          (float*)d_out, H, nbx);
}

// Round 16
// 30.745 us; speedup vs baseline: 1.5381x; 1.0078x over previous
//
#include <hip/hip_runtime.h>

#define DIM 120
#define NB 16            // batch rows per block
#define NBP 20           // padded LDS stride in dwords (b128-aligned)
#define BLOCK 256        // one thread per output row
#define NG (NB / 4)      // float4 groups along b
#define NXCD 8
#define SMEM_FLOATS (2 * DIM * NBP)   // 4800 floats = 19.2 KB (>= 16 KB outbuf)

typedef float f32x4 __attribute__((ext_vector_type(4)));   // nt-store-legal vec4

// ---- Fused preprocess: diff-based CSR row pointers + packed entries ----
// Every output row has >=1 entry, so oi is dense: row boundaries found by
// comparing neighbors (no binary search).
__global__ void pre_kernel(const int* __restrict__ oi, int K, int H,
                           int* __restrict__ row_start,
                           const int* __restrict__ i1, const int* __restrict__ i2,
                           const int* __restrict__ cb, const float* __restrict__ pal,
                           uint2* __restrict__ ent) {
    int k = blockIdx.x * blockDim.x + threadIdx.x;
    if (k < K) {
        uint2 e;
        e.x = (unsigned)i1[k] | ((unsigned)i2[k] << 16);
        e.y = __float_as_uint(pal[cb[k]]);
        ent[k] = e;
        const int cur = oi[k];
        const int prev = (k == 0) ? -1 : oi[k - 1];
        for (int o = prev + 1; o <= cur; ++o) row_start[o] = k;
    } else if (k == K) {
        const int prev = oi[K - 1];
        for (int o = prev + 1; o <= H; ++o) row_start[o] = K;
    }
}

// ---- Main: R15 structure; exchange reads hoisted ahead of nt stores ----
__global__ __launch_bounds__(BLOCK, 8) void tp_kernel(
    const float* __restrict__ in1, const float* __restrict__ in2,
    const uint2* __restrict__ ent, const int* __restrict__ row_start,
    float* __restrict__ out, int H, int nbx) {
    // bijective XCD-chunked swizzle over the o-block dimension
    int x = blockIdx.x;
    {
        const int q = nbx / NXCD, r = nbx % NXCD;
        const int xcd = x % NXCD, pos = x / NXCD;
        x = (xcd < r) ? (xcd * (q + 1) + pos) : (r * (q + 1) + (xcd - r) * q + pos);
    }

    __shared__ __align__(16) float smem[SMEM_FLOATS];
    float* __restrict__ s1t = smem;
    float* __restrict__ s2t = smem + DIM * NBP;

    // --- stage NB batch-rows transposed to [d][b] ---
    const int b0 = blockIdx.y * NB;
    for (int t = threadIdx.x; t < 2 * DIM * NG; t += BLOCK) {
        const int arr = (t >= DIM * NG);
        const int c = arr ? t - DIM * NG : t;
        const int d = c % DIM;
        const int g = c / DIM;
        const float* __restrict__ src = arr ? in2 : in1;
        const size_t base = (size_t)(b0 + 4 * g) * DIM + d;
        float4 v;
        v.x = src[base + 0 * DIM];
        v.y = src[base + 1 * DIM];
        v.z = src[base + 2 * DIM];
        v.w = src[base + 3 * DIM];
        float* dst = arr ? s2t : s1t;
        *(float4*)(dst + d * NBP + 4 * g) = v;
    }
    __syncthreads();

    const int o0 = x * BLOCK;
    const int o = o0 + (int)threadIdx.x;
    const bool act = (o < H);

    float acc[NB];
#pragma unroll
    for (int b = 0; b < NB; ++b) acc[b] = 0.0f;

    if (act) {
        const int k0 = row_start[o];
        const int k1 = row_start[o + 1];
        for (int k = k0; k < k1; ++k) {
            const uint2 e = ent[k];
            const float4* __restrict__ pa = (const float4*)(s1t + (e.x & 0xffffu) * NBP);
            const float4* __restrict__ pc = (const float4*)(s2t + (e.x >> 16) * NBP);
            const float v = __uint_as_float(e.y);
#pragma unroll
            for (int j = 0; j < NG; ++j) {
                const float4 x4 = pa[j];
                const float4 y4 = pc[j];
                acc[4 * j + 0] = fmaf(v * x4.x, y4.x, acc[4 * j + 0]);
                acc[4 * j + 1] = fmaf(v * x4.y, y4.y, acc[4 * j + 1]);
                acc[4 * j + 2] = fmaf(v * x4.z, y4.z, acc[4 * j + 2]);
                acc[4 * j + 3] = fmaf(v * x4.w, y4.w, acc[4 * j + 3]);
            }
        }
    }
    __syncthreads();   // staging reads complete before overwriting smem

    if (o0 + BLOCK <= H) {
        // exchange: outbuf[b][t] overlaid on smem (16 KB), stride-1 conflict-free
#pragma unroll
        for (int b = 0; b < NB; ++b)
            smem[b * BLOCK + threadIdx.x] = acc[b];
        __syncthreads();
        // wave w owns b = 4*it + w; hoist all LDS reads, then back-to-back
        // 1KB contiguous NT dwordx4 bursts (deeper store queue).
        const int wave = threadIdx.x >> 6;
        const int lane = threadIdx.x & 63;
        f32x4 vv[NB / 4];
#pragma unroll
        for (int it = 0; it < NB / 4; ++it)
            vv[it] = *(const f32x4*)(smem + (it * 4 + wave) * BLOCK + 4 * lane);
#pragma unroll
        for (int it = 0; it < NB / 4; ++it)
            __builtin_nontemporal_store(
                vv[it],
                (f32x4*)(out + (size_t)(b0 + it * 4 + wave) * H + o0 + 4 * lane));
    } else if (act) {
        // partial last tile: per-thread scalar nt stores
#pragma unroll
        for (int b = 0; b < NB; ++b)
            __builtin_nontemporal_store(acc[b], &out[(size_t)(b0 + b) * H + o]);
    }
}

extern "C" void kernel_launch(void* const* d_in, const int* in_sizes, int n_in,
                              void* d_out, int out_size, void* d_ws, size_t ws_size,
                              hipStream_t stream) {
    const float* in1 = (const float*)d_in[0];
    const float* in2 = (const float*)d_in[1];
    const float* pal = (const float*)d_in[2];
    const int*   i1  = (const int*)d_in[3];
    const int*   i2  = (const int*)d_in[4];
    const int*   oi  = (const int*)d_in[5];
    const int*   cb  = (const int*)d_in[6];

    const int K = in_sizes[3];
    const int B = in_sizes[0] / DIM;   // 2048
    const int H = out_size / B;        // 14400

    uint2* ent = (uint2*)d_ws;
    int* row_start = (int*)((char*)d_ws + (size_t)K * sizeof(uint2));

    pre_kernel<<<(K + 1 + 255) / 256, 256, 0, stream>>>(oi, K, H, row_start,
                                                        i1, i2, cb, pal, ent);

    const int nbx = (H + BLOCK - 1) / BLOCK;   // 57
    dim3 grid(nbx, B / NB);
    tp_kernel<<<grid, BLOCK, 0, stream>>>(in1, in2, ent, row_start,
                                          (float*)d_out, H, nbx);
}